// Round 2
// baseline (429.425 us; speedup 1.0000x reference)
//
#include <hip/hip_runtime.h>
#include <hip/hip_bf16.h>

#define EMB 1024
#define CTX 32
#define NEXP 16
#define H1 2048
#define H2 512
#define NBIG 16384  // F_IN*R == R*F_OUT

typedef __attribute__((ext_vector_type(8))) short short8;
typedef __attribute__((ext_vector_type(4))) float floatx4;

__device__ inline unsigned short bf_bits(float x) {
  unsigned u = __builtin_bit_cast(unsigned, x);
  u += 0x7fffu + ((u >> 16) & 1u);  // round-to-nearest-even
  return (unsigned short)(u >> 16);
}
__device__ inline unsigned pk_bf16(float a, float b) {
  return (unsigned)bf_bits(a) | ((unsigned)bf_bits(b) << 16);
}

// ---------------- K1a: g1 = relu(s @ Wg1 + bg1)  (8 x 2048) ----------------
__global__ void __launch_bounds__(256) k_gate1(const float* __restrict__ s,
                                               const float* __restrict__ Wg1,
                                               const float* __restrict__ bg1,
                                               float* __restrict__ g1) {
  __shared__ float red[16][16][8];
  int t = threadIdx.x;
  int c = t & 15, kk = t >> 4;
  int h = blockIdx.x * 16 + c;
  float acc[8];
#pragma unroll
  for (int b = 0; b < 8; ++b) acc[b] = 0.f;
  int k0 = kk * 64;
  for (int k = k0; k < k0 + 64; ++k) {
    float w = Wg1[(size_t)k * H1 + h];
#pragma unroll
    for (int b = 0; b < 8; ++b) acc[b] += s[b * EMB + k] * w;
  }
#pragma unroll
  for (int b = 0; b < 8; ++b) red[kk][c][b] = acc[b];
  __syncthreads();
  if (t < 128) {
    int cc = t >> 3, b = t & 7;
    float v = 0.f;
#pragma unroll
    for (int q = 0; q < 16; ++q) v += red[q][cc][b];
    int hh = blockIdx.x * 16 + cc;
    v += bg1[hh];
    g1[b * H1 + hh] = fmaxf(v, 0.f);
  }
}

// ---------------- K1b: logits = g1 @ Wg2 + bg2  (8 x 16) ----------------
__global__ void __launch_bounds__(256) k_gate2(const float* __restrict__ g1,
                                               const float* __restrict__ Wg2,
                                               const float* __restrict__ bg2,
                                               float* __restrict__ logits) {
  __shared__ float red[256][8];
  int e = blockIdx.x, t = threadIdx.x;
  int k0 = t * 8;
  float wv[8];
#pragma unroll
  for (int j = 0; j < 8; ++j) wv[j] = Wg2[(size_t)(k0 + j) * NEXP + e];
  float acc[8];
#pragma unroll
  for (int b = 0; b < 8; ++b) {
    float4 ga = *(const float4*)&g1[b * H1 + k0];
    float4 gb = *(const float4*)&g1[b * H1 + k0 + 4];
    acc[b] = ga.x * wv[0] + ga.y * wv[1] + ga.z * wv[2] + ga.w * wv[3] +
             gb.x * wv[4] + gb.y * wv[5] + gb.z * wv[6] + gb.w * wv[7];
  }
#pragma unroll
  for (int b = 0; b < 8; ++b) red[t][b] = acc[b];
  __syncthreads();
  for (int off = 128; off > 0; off >>= 1) {
    if (t < off) {
#pragma unroll
      for (int b = 0; b < 8; ++b) red[t][b] += red[t + off][b];
    }
    __syncthreads();
  }
  if (t < 8) logits[t * NEXP + e] = red[0][t] + bg2[e];
}

// ---------------- K2: base[e,b,h] = s @ W1s + b1  (16 x 8 x 2048) ----------------
// grid (16 htile, 16 e), block 512. Memory-bound on W1s (134 MB).
__global__ void __launch_bounds__(512) k_base(const float* __restrict__ s,
                                              const float* __restrict__ W1,
                                              const float* __restrict__ b1,
                                              float* __restrict__ base) {
  __shared__ float sl[8 * EMB];     // 32 KB
  __shared__ float red[8][64][17];  // 34 KB, +1 pad kills bank conflicts
  int t = threadIdx.x;
  int ht = blockIdx.x;
  int e = blockIdx.y;
#pragma unroll
  for (int i = 0; i < 4; ++i) {
    int idx = (t + i * 512) * 4;
    *(float4*)&sl[idx] = *(const float4*)&s[idx];
  }
  __syncthreads();
  int hp = t & 63;  // h-pair within tile
  int kk = t >> 6;  // 0..7 k-slice (wave-uniform)
  int h = ht * 128 + hp * 2;
  const float* wp = W1 + (size_t)e * 1056 * H1 + h;
  float a0[8], a1[8];
#pragma unroll
  for (int b = 0; b < 8; ++b) { a0[b] = 0.f; a1[b] = 0.f; }
  int k0 = kk * 128;
  for (int k = k0; k < k0 + 128; ++k) {
    float2 w = *(const float2*)(wp + (size_t)k * H1);
#pragma unroll
    for (int b = 0; b < 8; ++b) {
      float sv = sl[b * EMB + k];  // wave-uniform addr -> broadcast
      a0[b] += sv * w.x;
      a1[b] += sv * w.y;
    }
  }
#pragma unroll
  for (int b = 0; b < 8; ++b) {
    red[kk][hp][b * 2] = a0[b];
    red[kk][hp][b * 2 + 1] = a1[b];
  }
  __syncthreads();
  if (t < 64) {
    int hh = ht * 128 + t * 2;
#pragma unroll
    for (int b = 0; b < 8; ++b) {
      float v0 = 0.f, v1 = 0.f;
#pragma unroll
      for (int q = 0; q < 8; ++q) {
        v0 += red[q][t][b * 2];
        v1 += red[q][t][b * 2 + 1];
      }
      float2 bv = *(const float2*)&b1[e * H1 + hh];
      float2 o;
      o.x = v0 + bv.x;
      o.y = v1 + bv.y;
      *(float2*)&base[(size_t)(e * 8 + b) * H1 + hh] = o;
    }
  }
}

// ---------------- K3: eo[c,e,b,d] = relu(base+W1c) @ W2[e]  (bf16 MFMA) ----------------
// grid (8 dtile64, 4 mtile64, 16 e), block 256 (4 waves, one 16-wide n-tile each).
__global__ void __launch_bounds__(256) k_expert(const float* __restrict__ base,
                                                const float* __restrict__ W1,
                                                const float* __restrict__ W2,
                                                float* __restrict__ eo) {
  __shared__ __align__(16) unsigned short hl[64 * 64];  // bf16 A-tile, 128B rows, XOR-swizzled 16B chunks
  int dt = blockIdx.x, mt = blockIdx.y, e = blockIdx.z;
  int t = threadIdx.x;
  int lane = t & 63, w = t >> 6;
  int fr = lane & 15, quad = lane >> 4;
  int d = dt * 64 + w * 16 + fr;

  const float* baseE = base + (size_t)e * 8 * H1;
  const float* w1cE = W1 + (size_t)e * 1056 * H1 + (size_t)EMB * H1;
  const float* w2E = W2 + (size_t)e * H1 * H2;

  // formation mapping: each thread forms h[fm][fkp..fkp+15] of the 64x64 bf16 tile
  int fm = lane;
  int fb = fm & 7;
  int fc = mt * 8 + (fm >> 3);
  int fkp = w * 16;
  const float* bsrc = baseE + (size_t)fb * H1 + fkp;
  const float* csrc = w1cE + (size_t)fc * H1 + fkp;
  int xr = fm & 7;
  unsigned short* wp0 = &hl[fm * 64 + (((2 * w) ^ xr) * 8)];
  unsigned short* wp1 = &hl[fm * 64 + (((2 * w + 1) ^ xr) * 8)];

  floatx4 zero4 = {0.f, 0.f, 0.f, 0.f};
  floatx4 acc[4];
#pragma unroll
  for (int r = 0; r < 4; ++r) acc[r] = zero4;

  float4 rb[4], rc[4];
#pragma unroll
  for (int j = 0; j < 4; ++j) {
    rb[j] = *(const float4*)(bsrc + j * 4);
    rc[j] = *(const float4*)(csrc + j * 4);
  }

  for (int k0 = 0; k0 < H1; k0 += 64) {
    float hv[16];
#pragma unroll
    for (int j = 0; j < 4; ++j) {
      hv[j * 4 + 0] = fmaxf(rb[j].x + rc[j].x, 0.f);
      hv[j * 4 + 1] = fmaxf(rb[j].y + rc[j].y, 0.f);
      hv[j * 4 + 2] = fmaxf(rb[j].z + rc[j].z, 0.f);
      hv[j * 4 + 3] = fmaxf(rb[j].w + rc[j].w, 0.f);
    }
    union { short8 v; unsigned u[4]; } p0, p1;
#pragma unroll
    for (int j = 0; j < 4; ++j) {
      p0.u[j] = pk_bf16(hv[2 * j], hv[2 * j + 1]);
      p1.u[j] = pk_bf16(hv[8 + 2 * j], hv[8 + 2 * j + 1]);
    }
    __syncthreads();  // previous iteration's A-frag reads complete
    *(short8*)wp0 = p0.v;
    *(short8*)wp1 = p1.v;
    __syncthreads();  // tile visible
    if (k0 + 64 < H1) {  // prefetch next formation sources (overlaps MFMA phase)
#pragma unroll
      for (int j = 0; j < 4; ++j) {
        rb[j] = *(const float4*)(bsrc + k0 + 64 + j * 4);
        rc[j] = *(const float4*)(csrc + k0 + 64 + j * 4);
      }
    }
#pragma unroll
    for (int ks = 0; ks < 2; ++ks) {
      const float* wq = w2E + (size_t)(k0 + ks * 32 + quad * 8) * H2 + d;
      float f0 = wq[0], f1 = wq[H2], f2 = wq[2 * H2], f3 = wq[3 * H2];
      float f4 = wq[4 * H2], f5 = wq[5 * H2], f6 = wq[6 * H2], f7 = wq[7 * H2];
      union { short8 v; unsigned u[4]; } bp;
      bp.u[0] = pk_bf16(f0, f1);
      bp.u[1] = pk_bf16(f2, f3);
      bp.u[2] = pk_bf16(f4, f5);
      bp.u[3] = pk_bf16(f6, f7);
#pragma unroll
      for (int rt = 0; rt < 4; ++rt) {
        int m = rt * 16 + fr;
        short8 av = *(const short8*)&hl[m * 64 + (((ks * 4 + quad) ^ (m & 7)) * 8)];
        acc[rt] = __builtin_amdgcn_mfma_f32_16x16x32_bf16(av, bp.v, acc[rt], 0, 0, 0);
      }
    }
  }
#pragma unroll
  for (int rt = 0; rt < 4; ++rt) {
#pragma unroll
    for (int i = 0; i < 4; ++i) {
      int gm = mt * 64 + rt * 16 + quad * 4 + i;
      int cc = gm >> 3, bb = gm & 7;
      eo[(((size_t)cc * NEXP + e) * 8 + bb) * H2 + d] = acc[rt][i];
    }
  }
}

// ---------------- K4: z = sum_e softmax(logits)[b,e]*(eo+b2) -> bf16 ----------------
__global__ void __launch_bounds__(256) k_mix(const float* __restrict__ eo,
                                             const float* __restrict__ logits,
                                             const float* __restrict__ b2,
                                             unsigned short* __restrict__ zbf) {
  int dt = blockIdx.x;  // 8
  int c = blockIdx.y;   // 32
  int t = threadIdx.x;
  int d = dt * 64 + (t & 63);
  int bq = t >> 6;
#pragma unroll
  for (int bi = 0; bi < 2; ++bi) {
    int b = bq + bi * 4;
    float lg[16];
    float mx = -1e30f;
#pragma unroll
    for (int e2 = 0; e2 < 16; ++e2) {
      lg[e2] = logits[b * NEXP + e2];
      mx = fmaxf(mx, lg[e2]);
    }
    float sum = 0.f;
#pragma unroll
    for (int e2 = 0; e2 < 16; ++e2) {
      lg[e2] = __expf(lg[e2] - mx);
      sum += lg[e2];
    }
    float inv = 1.f / sum;
    float acc = 0.f;
#pragma unroll
    for (int e2 = 0; e2 < 16; ++e2) {
      float v = eo[(((size_t)c * NEXP + e2) * 8 + b) * H2 + d] + b2[e2 * H2 + d];
      acc += lg[e2] * v;
    }
    acc *= inv;
    zbf[((size_t)c * 8 + b) * H2 + d] = bf_bits(acc);
  }
}

// ---------------- K5: out = z_bf16 @ {WA,WB} + bias  (bf16 MFMA, LDS-free) ----------------
// grid (128 ntile128, 2 mtile128, 2 matsel), block 256 (4 waves, 32-wide n-slice each).
__global__ void __launch_bounds__(256) k_lora(const unsigned short* __restrict__ zbf,
                                              const float* __restrict__ WA,
                                              const float* __restrict__ bA,
                                              const float* __restrict__ WB,
                                              const float* __restrict__ bB,
                                              float* __restrict__ out) {
  int nb = blockIdx.x, mt = blockIdx.y, ms = blockIdx.z;
  const float* W = ms ? WB : WA;
  const float* bias = ms ? bB : bA;
  float* o = out + (size_t)ms * 4194304;
  int t = threadIdx.x;
  int lane = t & 63, w = t >> 6;
  int fr = lane & 15, quad = lane >> 4;
  int m0 = mt * 128;
  int n0 = nb * 128 + w * 32;

  floatx4 zero4 = {0.f, 0.f, 0.f, 0.f};
  floatx4 acc[8][2];
#pragma unroll
  for (int r = 0; r < 8; ++r) {
    acc[r][0] = zero4;
    acc[r][1] = zero4;
  }
  for (int k0 = 0; k0 < H2; k0 += 32) {
    short8 af[8];
#pragma unroll
    for (int rt = 0; rt < 8; ++rt) {
      int m = m0 + rt * 16 + fr;
      af[rt] = *(const short8*)&zbf[(size_t)m * H2 + k0 + quad * 8];
    }
#pragma unroll
    for (int nt = 0; nt < 2; ++nt) {
      int n = n0 + nt * 16 + fr;
      const float* wq = W + (size_t)(k0 + quad * 8) * NBIG + n;
      float f0 = wq[0], f1 = wq[NBIG], f2 = wq[2 * NBIG], f3 = wq[3 * NBIG];
      float f4 = wq[4 * NBIG], f5 = wq[5 * NBIG], f6 = wq[6 * NBIG], f7 = wq[7 * NBIG];
      union { short8 v; unsigned u[4]; } bp;
      bp.u[0] = pk_bf16(f0, f1);
      bp.u[1] = pk_bf16(f2, f3);
      bp.u[2] = pk_bf16(f4, f5);
      bp.u[3] = pk_bf16(f6, f7);
#pragma unroll
      for (int rt = 0; rt < 8; ++rt)
        acc[rt][nt] = __builtin_amdgcn_mfma_f32_16x16x32_bf16(af[rt], bp.v, acc[rt][nt], 0, 0, 0);
    }
  }
#pragma unroll
  for (int nt = 0; nt < 2; ++nt) {
    int n = n0 + nt * 16 + fr;
    float bv = bias[n];
#pragma unroll
    for (int rt = 0; rt < 8; ++rt) {
#pragma unroll
      for (int i = 0; i < 4; ++i) {
        int m = m0 + rt * 16 + quad * 4 + i;
        o[(size_t)m * NBIG + n] = acc[rt][nt][i] + bv;
      }
    }
  }
}

extern "C" void kernel_launch(void* const* d_in, const int* in_sizes, int n_in,
                              void* d_out, int out_size, void* d_ws, size_t ws_size,
                              hipStream_t stream) {
  const float* s = (const float*)d_in[0];
  const float* Wg1 = (const float*)d_in[1];
  const float* bg1 = (const float*)d_in[2];
  const float* Wg2 = (const float*)d_in[3];
  const float* bg2 = (const float*)d_in[4];
  const float* W1 = (const float*)d_in[5];
  const float* b1 = (const float*)d_in[6];
  const float* W2 = (const float*)d_in[7];
  const float* b2 = (const float*)d_in[8];
  const float* WA = (const float*)d_in[9];
  const float* bA = (const float*)d_in[10];
  const float* WB = (const float*)d_in[11];
  const float* bB = (const float*)d_in[12];
  float* out = (float*)d_out;

  char* ws = (char*)d_ws;
  float* g1 = (float*)(ws);                                  // 64 KB
  float* logits = (float*)(ws + 65536);                      // 512 B
  float* base = (float*)(ws + 131072);                       // 1 MB
  float* eo = (float*)(ws + 131072 + 1048576);               // 8.39 MB
  unsigned short* zbf = (unsigned short*)(ws + 131072 + 1048576 + 8388608);  // 256 KB

  k_gate1<<<128, 256, 0, stream>>>(s, Wg1, bg1, g1);
  k_gate2<<<16, 256, 0, stream>>>(g1, Wg2, bg2, logits);
  k_base<<<dim3(16, 16), 512, 0, stream>>>(s, W1, b1, base);
  k_expert<<<dim3(8, 4, 16), 256, 0, stream>>>(base, W1, W2, eo);
  k_mix<<<dim3(8, 32), 256, 0, stream>>>(eo, logits, b2, zbf);
  k_lora<<<dim3(128, 2, 2), 256, 0, stream>>>(zbf, WA, bA, WB, bB, out);
}